// Round 3
// baseline (1940.445 us; speedup 1.0000x reference)
//
#include <hip/hip_runtime.h>

#define N_NODES 131072
#define BGRAPHS 512
#define FDIM    512
#define HDIM    256
#define NPG     256
#define KSEL    128
#define STAGES  16            // K = 512 / 32
#define STAGE_UNITS 3072      // 3 splits * 2 q * 8 ntiles * 64 lanes
#define STAGE_BYTES (STAGE_UNITS * 16)   // 48 KB

typedef __attribute__((ext_vector_type(8)))  short bf16x8;
typedef __attribute__((ext_vector_type(16))) float f32x16;

// RNE float -> bf16 (bit trick), also returns the bf16 value as float
__device__ __forceinline__ unsigned short bf16_rne(float f, float* back) {
    unsigned u = __float_as_uint(f);
    unsigned r = u + 0x7FFFu + ((u >> 16) & 1u);
    unsigned short h = (unsigned short)(r >> 16);
    *back = __uint_as_float(((unsigned)h) << 16);
    return h;
}

// ---------------------------------------------------------------------------
// K0: split W1 (fp32 [512][256]) into 3 bf16 planes in MFMA B-fragment order:
// unit (((s*3+p)*2+q)*8+nt)*64+lane, 8 bf16 each,
// elem j = W1[s*32+q*16+(lane>>5)*8+j][nt*32+(lane&31)]  (split p).
// ---------------------------------------------------------------------------
__global__ __launch_bounds__(256)
void split_w1_kernel(const float* __restrict__ W1, unsigned short* __restrict__ wsB)
{
    const int uid  = blockIdx.x * 256 + threadIdx.x;     // 0..49151
    const int lane = uid & 63;
    int t = uid >> 6;
    const int nt = t & 7;  t >>= 3;
    const int q  = t & 1;  t >>= 1;
    const int p  = t % 3;
    const int s  = t / 3;
    const int n  = nt * 32 + (lane & 31);
    const int k0 = s * 32 + q * 16 + (lane >> 5) * 8;

    bf16x8 v;
    #pragma unroll
    for (int j = 0; j < 8; ++j) {
        float w = W1[(size_t)(k0 + j) * HDIM + n];
        float f1, f2, f3;
        unsigned short h1 = bf16_rne(w, &f1);
        float r1 = w - f1;
        unsigned short h2 = bf16_rne(r1, &f2);
        float r2 = r1 - f2;
        unsigned short h3 = bf16_rne(r2, &f3);
        v[j] = (short)(p == 0 ? h1 : (p == 1 ? h2 : h3));
    }
    *(bf16x8*)(wsB + (size_t)uid * 8) = v;
}

// ---------------------------------------------------------------------------
// K1 (FUSED): one block per graph (256 rows), 512 threads = 8 waves.
//   phase A: split-bf16 MFMA GEMM 256x256, K=512 (scores)
//   phase B: in-block rank selection (stable lexsort semantics) + mask write
//   phase C: pooled gather of the 128 selected rows (L2/L3-warm)
//   phase D: per-graph margin loss -> ws
// ---------------------------------------------------------------------------
__global__ __launch_bounds__(512, 4)
void fused_kernel(const float* __restrict__ x,
                  const unsigned short* __restrict__ wsB,
                  const float* __restrict__ b1, const float* __restrict__ W2,
                  const float* __restrict__ b2,
                  float* __restrict__ pooled, float* __restrict__ mask_out,
                  float* __restrict__ loss_per_g)
{
    __shared__ unsigned short ldsB[STAGE_BYTES / 2];  // 48 KB
    __shared__ float Sp[2][NPG];                      // 2 KB  score partials
    __shared__ float sv[NPG];                         // 1 KB  final scores
    __shared__ int   selr[KSEL];                      // 512 B selected rows (rank order)
    __shared__ float redT[NPG];
    __shared__ float redS[NPG];

    const int g    = blockIdx.x;
    const int tid  = threadIdx.x;
    const int lane = tid & 63;
    const int wv   = tid >> 6;        // 0..7
    const int wy   = wv & 3;          // row quarter (64 rows)
    const int wx   = wv >> 2;         // col half (128 cols)
    const int l31  = lane & 31;
    const int lh   = lane >> 5;
    const int m_base = g * NPG + wy * 64;

    f32x16 acc[2][4];
    #pragma unroll
    for (int a = 0; a < 2; ++a)
        #pragma unroll
        for (int b = 0; b < 4; ++b)
            #pragma unroll
            for (int r = 0; r < 16; ++r) acc[a][b][r] = 0.f;

    for (int s = 0; s < STAGES; ++s) {
        __syncthreads();
        const unsigned short* src = wsB + (size_t)s * (STAGE_BYTES / 2);
        #pragma unroll
        for (int i = 0; i < 6; ++i) {
            const int unit = i * 512 + tid;   // wave-contiguous, lane-ordered
            __builtin_amdgcn_global_load_lds(
                (const __attribute__((address_space(1))) unsigned int*)(src + (size_t)unit * 8),
                (__attribute__((address_space(3))) unsigned int*)(ldsB + unit * 8),
                16, 0, 0);
        }
        __syncthreads();

        #pragma unroll
        for (int q = 0; q < 2; ++q) {
            float4 xa[2], xb[2];
            #pragma unroll
            for (int mt = 0; mt < 2; ++mt) {
                const int row = m_base + mt * 32 + l31;
                const float* xp = x + (size_t)row * FDIM + s * 32 + q * 16 + lh * 8;
                xa[mt] = *(const float4*)xp;
                xb[mt] = *(const float4*)(xp + 4);
            }
            const bf16x8* bfp = (const bf16x8*)ldsB;
            bf16x8 Bh[4], Bm[4], Bl[4];
            #pragma unroll
            for (int nt = 0; nt < 4; ++nt) {
                const int nn = wx * 4 + nt;
                Bh[nt] = bfp[((0 * 2 + q) * 8 + nn) * 64 + lane];
                Bm[nt] = bfp[((1 * 2 + q) * 8 + nn) * 64 + lane];
                Bl[nt] = bfp[((2 * 2 + q) * 8 + nn) * 64 + lane];
            }
            #pragma unroll
            for (int mt = 0; mt < 2; ++mt) {
                float v[8] = {xa[mt].x, xa[mt].y, xa[mt].z, xa[mt].w,
                              xb[mt].x, xb[mt].y, xb[mt].z, xb[mt].w};
                bf16x8 Ah, Am, Al;
                #pragma unroll
                for (int j = 0; j < 8; ++j) {
                    float f1, f2, f3;
                    unsigned short h1 = bf16_rne(v[j], &f1);
                    float r1 = v[j] - f1;
                    unsigned short h2 = bf16_rne(r1, &f2);
                    float r2 = r1 - f2;
                    unsigned short h3 = bf16_rne(r2, &f3);
                    Ah[j] = (short)h1; Am[j] = (short)h2; Al[j] = (short)h3;
                }
                #pragma unroll
                for (int nt = 0; nt < 4; ++nt) {
                    acc[mt][nt] = __builtin_amdgcn_mfma_f32_32x32x16_bf16(Ah, Bh[nt], acc[mt][nt], 0, 0, 0);
                    acc[mt][nt] = __builtin_amdgcn_mfma_f32_32x32x16_bf16(Ah, Bm[nt], acc[mt][nt], 0, 0, 0);
                    acc[mt][nt] = __builtin_amdgcn_mfma_f32_32x32x16_bf16(Am, Bh[nt], acc[mt][nt], 0, 0, 0);
                    acc[mt][nt] = __builtin_amdgcn_mfma_f32_32x32x16_bf16(Ah, Bl[nt], acc[mt][nt], 0, 0, 0);
                    acc[mt][nt] = __builtin_amdgcn_mfma_f32_32x32x16_bf16(Al, Bh[nt], acc[mt][nt], 0, 0, 0);
                    acc[mt][nt] = __builtin_amdgcn_mfma_f32_32x32x16_bf16(Am, Bm[nt], acc[mt][nt], 0, 0, 0);
                }
            }
        }
    }

    // ---- phase B epilogue: per-row score partial = sum_cols relu(h+b1)*W2
    float bb[4], ww[4];
    #pragma unroll
    for (int nt = 0; nt < 4; ++nt) {
        const int c = wx * 128 + nt * 32 + l31;
        bb[nt] = b1[c];
        ww[nt] = W2[c];
    }
    #pragma unroll
    for (int mt = 0; mt < 2; ++mt) {
        float pr[16];
        #pragma unroll
        for (int r = 0; r < 16; ++r) pr[r] = 0.f;
        #pragma unroll
        for (int nt = 0; nt < 4; ++nt)
            #pragma unroll
            for (int r = 0; r < 16; ++r) {
                float h = acc[mt][nt][r] + bb[nt];
                h = h > 0.f ? h : 0.f;
                pr[r] = fmaf(h, ww[nt], pr[r]);
            }
        #pragma unroll
        for (int mask = 1; mask <= 16; mask <<= 1)
            #pragma unroll
            for (int r = 0; r < 16; ++r)
                pr[r] += __shfl_xor(pr[r], mask);
        if (l31 == 0) {
            #pragma unroll
            for (int r = 0; r < 16; ++r) {
                const int row = wy * 64 + mt * 32 + (r & 3) + 8 * (r >> 2) + 4 * lh;
                Sp[wx][row] = pr[r];
            }
        }
    }
    __syncthreads();

    float sc = 0.f;
    if (tid < NPG) {
        sc = b2[0] + Sp[0][tid] + Sp[1][tid];
        sv[tid] = sc;
    }
    __syncthreads();

    // ---- selection: exact rank (score desc, index asc on ties)
    bool sel = false;
    if (tid < NPG) {
        int rank = 0;
        for (int j = 0; j < NPG; ++j) {
            const float sj = sv[j];
            rank += (sj > sc || (sj == sc && j < tid)) ? 1 : 0;
        }
        sel = rank < KSEL;
        mask_out[g * NPG + tid] = sel ? 1.0f : 0.0f;
        if (sel) selr[rank] = tid;
        redT[tid] = sc;
        redS[tid] = sel ? sc : 0.f;
    }
    __syncthreads();

    // ---- phase D: margin loss (tree-reduce the 256 entries)
    for (int off = 128; off > 0; off >>= 1) {
        if (tid < off) { redT[tid] += redT[tid + off]; redS[tid] += redS[tid + off]; }
        __syncthreads();
    }
    if (tid == 0) {
        const float tot = redT[0], ssum = redS[0];
        const float sel_mean = ssum * (1.0f / KSEL);
        const float uns_mean = (tot - ssum) * (1.0f / (NPG - KSEL));
        const float v = 0.5f - (sel_mean - uns_mean);
        loss_per_g[g] = v > 0.f ? v : 0.f;
    }

    // ---- phase C: pooled gather; col per thread, rows L2/L3-warm
    const int col = tid;                         // 512 cols, 512 threads
    const float* __restrict__ xg = x + (size_t)g * NPG * FDIM;
    float a0 = 0.f, a1 = 0.f, a2 = 0.f, a3 = 0.f;
    #pragma unroll 4
    for (int n = 0; n < KSEL; n += 4) {
        a0 += xg[(size_t)selr[n + 0] * FDIM + col];
        a1 += xg[(size_t)selr[n + 1] * FDIM + col];
        a2 += xg[(size_t)selr[n + 2] * FDIM + col];
        a3 += xg[(size_t)selr[n + 3] * FDIM + col];
    }
    pooled[g * FDIM + col] = (a0 + a1) + (a2 + a3);
}

// ---------------------------------------------------------------------------
// K2: topk_loss = sum(loss_per_g) / B * 0.2
// ---------------------------------------------------------------------------
__global__ __launch_bounds__(256)
void loss_kernel(const float* __restrict__ loss_per_g, float* __restrict__ out_loss)
{
    __shared__ float red[256];
    const int t = threadIdx.x;
    red[t] = loss_per_g[t] + loss_per_g[t + 256];
    __syncthreads();
    for (int off = 128; off > 0; off >>= 1) {
        if (t < off) red[t] += red[t + off];
        __syncthreads();
    }
    if (t == 0) out_loss[0] = red[0] * (0.2f / BGRAPHS);
}

extern "C" void kernel_launch(void* const* d_in, const int* in_sizes, int n_in,
                              void* d_out, int out_size, void* d_ws, size_t ws_size,
                              hipStream_t stream)
{
    const float* x  = (const float*)d_in[0];
    const float* W1 = (const float*)d_in[2];
    const float* b1 = (const float*)d_in[3];
    const float* W2 = (const float*)d_in[4];
    const float* b2 = (const float*)d_in[5];

    float* out    = (float*)d_out;
    float* pooled = out;                       // [512*512]
    float* loss   = out + BGRAPHS * FDIM;      // [1]
    float* mask   = loss + 1;                  // [131072]

    float* loss_g       = (float*)d_ws;                               // 2 KB
    unsigned short* wsB = (unsigned short*)((char*)d_ws + 4096);      // 768 KB

    split_w1_kernel<<<192, 256, 0, stream>>>(W1, wsB);
    fused_kernel<<<BGRAPHS, 512, 0, stream>>>(x, wsB, b1, W2, b2,
                                              pooled, mask, loss_g);
    loss_kernel<<<1, 256, 0, stream>>>(loss_g, loss);
}

// Round 4
// 506.371 us; speedup vs baseline: 3.8321x; 3.8321x over previous
//
#include <hip/hip_runtime.h>

#define N_NODES 131072
#define BGRAPHS 512
#define FDIM    512
#define HDIM    256
#define NPG     256
#define KSEL    128
#define STAGES  16            // K = 512 / 32
#define STAGE_UNITS 3072      // 3 splits * 2 q * 8 ntiles * 64 lanes
#define STAGE_BYTES (STAGE_UNITS * 16)   // 48 KB

typedef __attribute__((ext_vector_type(8)))  short bf16x8;
typedef __attribute__((ext_vector_type(16))) float f32x16;

// RNE float -> bf16 (bit trick), also returns the bf16 value as float
__device__ __forceinline__ unsigned short bf16_rne(float f, float* back) {
    unsigned u = __float_as_uint(f);
    unsigned r = u + 0x7FFFu + ((u >> 16) & 1u);
    unsigned short h = (unsigned short)(r >> 16);
    *back = __uint_as_float(((unsigned)h) << 16);
    return h;
}

// ---------------------------------------------------------------------------
// K0: split W1 (fp32 [512][256]) into 3 bf16 planes in MFMA B-fragment order:
// unit (((s*3+p)*2+q)*8+nt)*64+lane, 8 bf16 each,
// elem j = W1[s*32+q*16+(lane>>5)*8+j][nt*32+(lane&31)]  (split p).
// ---------------------------------------------------------------------------
__global__ __launch_bounds__(256)
void split_w1_kernel(const float* __restrict__ W1, unsigned short* __restrict__ wsB)
{
    const int uid  = blockIdx.x * 256 + threadIdx.x;     // 0..49151
    const int lane = uid & 63;
    int t = uid >> 6;
    const int nt = t & 7;  t >>= 3;
    const int q  = t & 1;  t >>= 1;
    const int p  = t % 3;
    const int s  = t / 3;
    const int n  = nt * 32 + (lane & 31);
    const int k0 = s * 32 + q * 16 + (lane >> 5) * 8;

    bf16x8 v;
    #pragma unroll
    for (int j = 0; j < 8; ++j) {
        float w = W1[(size_t)(k0 + j) * HDIM + n];
        float f1, f2, f3;
        unsigned short h1 = bf16_rne(w, &f1);
        float r1 = w - f1;
        unsigned short h2 = bf16_rne(r1, &f2);
        float r2 = r1 - f2;
        unsigned short h3 = bf16_rne(r2, &f3);
        v[j] = (short)(p == 0 ? h1 : (p == 1 ? h2 : h3));
    }
    *(bf16x8*)(wsB + (size_t)uid * 8) = v;
}

// ---------------------------------------------------------------------------
// K1 (FUSED): one block per graph (256 rows), 512 threads = 8 waves.
//   phase A: split-bf16 MFMA GEMM 256x256, K=512 (scores)
//   phase B: in-block rank selection (stable lexsort semantics) + mask write
//   phase C: pooled gather of the 128 selected rows (L2/L3-warm)
//   phase D: per-graph margin loss -> ws
// launch_bounds(512, 2): 2 waves/SIMD -> 256 regs/wave (128 VGPR + acc in
// unified file). (512,4) spilled the 128-reg accumulator -> 3.6 GB scratch.
// ---------------------------------------------------------------------------
__global__ __launch_bounds__(512, 2)
void fused_kernel(const float* __restrict__ x,
                  const unsigned short* __restrict__ wsB,
                  const float* __restrict__ b1, const float* __restrict__ W2,
                  const float* __restrict__ b2,
                  float* __restrict__ pooled, float* __restrict__ mask_out,
                  float* __restrict__ loss_per_g)
{
    __shared__ unsigned short ldsB[STAGE_BYTES / 2];  // 48 KB
    __shared__ float Sp[2][NPG];                      // 2 KB  score partials
    __shared__ float sv[NPG];                         // 1 KB  final scores
    __shared__ int   selr[KSEL];                      // 512 B selected rows (rank order)
    __shared__ float redT[NPG];
    __shared__ float redS[NPG];

    const int g    = blockIdx.x;
    const int tid  = threadIdx.x;
    const int lane = tid & 63;
    const int wv   = tid >> 6;        // 0..7
    const int wy   = wv & 3;          // row quarter (64 rows)
    const int wx   = wv >> 2;         // col half (128 cols)
    const int l31  = lane & 31;
    const int lh   = lane >> 5;
    const int m_base = g * NPG + wy * 64;

    f32x16 acc[2][4];
    #pragma unroll
    for (int a = 0; a < 2; ++a)
        #pragma unroll
        for (int b = 0; b < 4; ++b)
            #pragma unroll
            for (int r = 0; r < 16; ++r) acc[a][b][r] = 0.f;

    for (int s = 0; s < STAGES; ++s) {
        __syncthreads();
        const unsigned short* src = wsB + (size_t)s * (STAGE_BYTES / 2);
        #pragma unroll
        for (int i = 0; i < 6; ++i) {
            const int unit = i * 512 + tid;   // wave-contiguous, lane-ordered
            __builtin_amdgcn_global_load_lds(
                (const __attribute__((address_space(1))) unsigned int*)(src + (size_t)unit * 8),
                (__attribute__((address_space(3))) unsigned int*)(ldsB + unit * 8),
                16, 0, 0);
        }
        __syncthreads();

        #pragma unroll
        for (int q = 0; q < 2; ++q) {
            float4 xa[2], xb[2];
            #pragma unroll
            for (int mt = 0; mt < 2; ++mt) {
                const int row = m_base + mt * 32 + l31;
                const float* xp = x + (size_t)row * FDIM + s * 32 + q * 16 + lh * 8;
                xa[mt] = *(const float4*)xp;
                xb[mt] = *(const float4*)(xp + 4);
            }
            const bf16x8* bfp = (const bf16x8*)ldsB;
            bf16x8 Bh[4], Bm[4], Bl[4];
            #pragma unroll
            for (int nt = 0; nt < 4; ++nt) {
                const int nn = wx * 4 + nt;
                Bh[nt] = bfp[((0 * 2 + q) * 8 + nn) * 64 + lane];
                Bm[nt] = bfp[((1 * 2 + q) * 8 + nn) * 64 + lane];
                Bl[nt] = bfp[((2 * 2 + q) * 8 + nn) * 64 + lane];
            }
            #pragma unroll
            for (int mt = 0; mt < 2; ++mt) {
                float v[8] = {xa[mt].x, xa[mt].y, xa[mt].z, xa[mt].w,
                              xb[mt].x, xb[mt].y, xb[mt].z, xb[mt].w};
                bf16x8 Ah, Am, Al;
                #pragma unroll
                for (int j = 0; j < 8; ++j) {
                    float f1, f2, f3;
                    unsigned short h1 = bf16_rne(v[j], &f1);
                    float r1 = v[j] - f1;
                    unsigned short h2 = bf16_rne(r1, &f2);
                    float r2 = r1 - f2;
                    unsigned short h3 = bf16_rne(r2, &f3);
                    Ah[j] = (short)h1; Am[j] = (short)h2; Al[j] = (short)h3;
                }
                #pragma unroll
                for (int nt = 0; nt < 4; ++nt) {
                    acc[mt][nt] = __builtin_amdgcn_mfma_f32_32x32x16_bf16(Ah, Bh[nt], acc[mt][nt], 0, 0, 0);
                    acc[mt][nt] = __builtin_amdgcn_mfma_f32_32x32x16_bf16(Ah, Bm[nt], acc[mt][nt], 0, 0, 0);
                    acc[mt][nt] = __builtin_amdgcn_mfma_f32_32x32x16_bf16(Am, Bh[nt], acc[mt][nt], 0, 0, 0);
                    acc[mt][nt] = __builtin_amdgcn_mfma_f32_32x32x16_bf16(Ah, Bl[nt], acc[mt][nt], 0, 0, 0);
                    acc[mt][nt] = __builtin_amdgcn_mfma_f32_32x32x16_bf16(Al, Bh[nt], acc[mt][nt], 0, 0, 0);
                    acc[mt][nt] = __builtin_amdgcn_mfma_f32_32x32x16_bf16(Am, Bm[nt], acc[mt][nt], 0, 0, 0);
                }
            }
        }
    }

    // ---- phase B epilogue: per-row score partial = sum_cols relu(h+b1)*W2
    float bb[4], ww[4];
    #pragma unroll
    for (int nt = 0; nt < 4; ++nt) {
        const int c = wx * 128 + nt * 32 + l31;
        bb[nt] = b1[c];
        ww[nt] = W2[c];
    }
    #pragma unroll
    for (int mt = 0; mt < 2; ++mt) {
        float pr[16];
        #pragma unroll
        for (int r = 0; r < 16; ++r) pr[r] = 0.f;
        #pragma unroll
        for (int nt = 0; nt < 4; ++nt)
            #pragma unroll
            for (int r = 0; r < 16; ++r) {
                float h = acc[mt][nt][r] + bb[nt];
                h = h > 0.f ? h : 0.f;
                pr[r] = fmaf(h, ww[nt], pr[r]);
            }
        #pragma unroll
        for (int mask = 1; mask <= 16; mask <<= 1)
            #pragma unroll
            for (int r = 0; r < 16; ++r)
                pr[r] += __shfl_xor(pr[r], mask);
        if (l31 == 0) {
            #pragma unroll
            for (int r = 0; r < 16; ++r) {
                const int row = wy * 64 + mt * 32 + (r & 3) + 8 * (r >> 2) + 4 * lh;
                Sp[wx][row] = pr[r];
            }
        }
    }
    __syncthreads();

    float sc = 0.f;
    if (tid < NPG) {
        sc = b2[0] + Sp[0][tid] + Sp[1][tid];
        sv[tid] = sc;
    }
    __syncthreads();

    // ---- selection: exact rank (score desc, index asc on ties)
    bool sel = false;
    if (tid < NPG) {
        int rank = 0;
        for (int j = 0; j < NPG; ++j) {
            const float sj = sv[j];
            rank += (sj > sc || (sj == sc && j < tid)) ? 1 : 0;
        }
        sel = rank < KSEL;
        mask_out[g * NPG + tid] = sel ? 1.0f : 0.0f;
        if (sel) selr[rank] = tid;
        redT[tid] = sc;
        redS[tid] = sel ? sc : 0.f;
    }
    __syncthreads();

    // ---- phase D: margin loss (tree-reduce the 256 entries)
    for (int off = 128; off > 0; off >>= 1) {
        if (tid < off) { redT[tid] += redT[tid + off]; redS[tid] += redS[tid + off]; }
        __syncthreads();
    }
    if (tid == 0) {
        const float tot = redT[0], ssum = redS[0];
        const float sel_mean = ssum * (1.0f / KSEL);
        const float uns_mean = (tot - ssum) * (1.0f / (NPG - KSEL));
        const float v = 0.5f - (sel_mean - uns_mean);
        loss_per_g[g] = v > 0.f ? v : 0.f;
    }

    // ---- phase C: pooled gather; col per thread, rows L2/L3-warm
    const int col = tid;                         // 512 cols, 512 threads
    const float* __restrict__ xg = x + (size_t)g * NPG * FDIM;
    float a0 = 0.f, a1 = 0.f, a2 = 0.f, a3 = 0.f;
    #pragma unroll 4
    for (int n = 0; n < KSEL; n += 4) {
        a0 += xg[(size_t)selr[n + 0] * FDIM + col];
        a1 += xg[(size_t)selr[n + 1] * FDIM + col];
        a2 += xg[(size_t)selr[n + 2] * FDIM + col];
        a3 += xg[(size_t)selr[n + 3] * FDIM + col];
    }
    pooled[g * FDIM + col] = (a0 + a1) + (a2 + a3);
}

// ---------------------------------------------------------------------------
// K2: topk_loss = sum(loss_per_g) / B * 0.2
// ---------------------------------------------------------------------------
__global__ __launch_bounds__(256)
void loss_kernel(const float* __restrict__ loss_per_g, float* __restrict__ out_loss)
{
    __shared__ float red[256];
    const int t = threadIdx.x;
    red[t] = loss_per_g[t] + loss_per_g[t + 256];
    __syncthreads();
    for (int off = 128; off > 0; off >>= 1) {
        if (t < off) red[t] += red[t + off];
        __syncthreads();
    }
    if (t == 0) out_loss[0] = red[0] * (0.2f / BGRAPHS);
}

extern "C" void kernel_launch(void* const* d_in, const int* in_sizes, int n_in,
                              void* d_out, int out_size, void* d_ws, size_t ws_size,
                              hipStream_t stream)
{
    const float* x  = (const float*)d_in[0];
    const float* W1 = (const float*)d_in[2];
    const float* b1 = (const float*)d_in[3];
    const float* W2 = (const float*)d_in[4];
    const float* b2 = (const float*)d_in[5];

    float* out    = (float*)d_out;
    float* pooled = out;                       // [512*512]
    float* loss   = out + BGRAPHS * FDIM;      // [1]
    float* mask   = loss + 1;                  // [131072]

    float* loss_g       = (float*)d_ws;                               // 2 KB
    unsigned short* wsB = (unsigned short*)((char*)d_ws + 4096);      // 768 KB

    split_w1_kernel<<<192, 256, 0, stream>>>(W1, wsB);
    fused_kernel<<<BGRAPHS, 512, 0, stream>>>(x, wsB, b1, W2, b2,
                                              pooled, mask, loss_g);
    loss_kernel<<<1, 256, 0, stream>>>(loss_g, loss);
}

// Round 5
// 476.451 us; speedup vs baseline: 4.0727x; 1.0628x over previous
//
#include <hip/hip_runtime.h>

#define N_NODES 131072
#define BGRAPHS 512
#define FDIM    512
#define HDIM    256
#define NPG     256
#define KSEL    128
#define STAGES  16                 // K = 512 / 32
#define BSTAGE_SHORTS 24576        // 48 KB of B per stage (3 splits * 2 q * 8 nt * 64 lanes * 8 bf16)
#define A_ROW   40                 // A-plane row stride in shorts (32 + 8 pad, keeps 16B align)
#define A_PLANE (NPG * A_ROW)      // 10240 shorts per split plane

typedef __attribute__((ext_vector_type(8)))  short bf16x8;
typedef __attribute__((ext_vector_type(16))) float f32x16;

// RNE float -> bf16 (bit trick), also returns the bf16 value as float
__device__ __forceinline__ unsigned short bf16_rne(float f, float* back) {
    unsigned u = __float_as_uint(f);
    unsigned r = u + 0x7FFFu + ((u >> 16) & 1u);
    unsigned short h = (unsigned short)(r >> 16);
    *back = __uint_as_float(((unsigned)h) << 16);
    return h;
}

// ---------------------------------------------------------------------------
// K0: split W1 (fp32 [512][256]) into 3 bf16 planes in MFMA B-fragment order.
// uid = s*3072 + ((q*3 + p)*8 + nt)*64 + lane, 8 bf16 each,
// elem j = W1[s*32 + q*16 + (lane>>5)*8 + j][nt*32 + (lane&31)]  (split p).
// ---------------------------------------------------------------------------
__global__ __launch_bounds__(256)
void split_w1_kernel(const float* __restrict__ W1, unsigned short* __restrict__ wsB)
{
    const int uid  = blockIdx.x * 256 + threadIdx.x;     // 0..49151
    const int lane = uid & 63;
    int t = uid >> 6;
    const int nt = t & 7;  t >>= 3;
    const int p  = t % 3;  t /= 3;
    const int q  = t & 1;
    const int s  = t >> 1;
    const int n  = nt * 32 + (lane & 31);
    const int k0 = s * 32 + q * 16 + (lane >> 5) * 8;

    bf16x8 v;
    #pragma unroll
    for (int j = 0; j < 8; ++j) {
        float w = W1[(size_t)(k0 + j) * HDIM + n];
        float f1, f2, f3;
        unsigned short h1 = bf16_rne(w, &f1);
        float r1 = w - f1;
        unsigned short h2 = bf16_rne(r1, &f2);
        float r2 = r1 - f2;
        unsigned short h3 = bf16_rne(r2, &f3);
        v[j] = (short)(p == 0 ? h1 : (p == 1 ? h2 : h3));
    }
    *(bf16x8*)(wsB + (size_t)uid * 8) = v;
}

// ---------------------------------------------------------------------------
// K1 (FUSED, pipelined): one block per graph, 512 threads = 8 waves.
// LDS: B double-buffer 2x48KB + A-split 3 planes 60KB = 156KB (epilogue
// overlays B region after the K-loop). A prefetched to regs 1 stage ahead;
// split once per block into LDS; B staged async 1 stage ahead.
// ---------------------------------------------------------------------------
__global__ __launch_bounds__(512, 2)
void fused_kernel(const float* __restrict__ x,
                  const unsigned short* __restrict__ wsB,
                  const float* __restrict__ b1, const float* __restrict__ W2,
                  const float* __restrict__ b2,
                  float* __restrict__ pooled, float* __restrict__ mask_out,
                  float* __restrict__ loss_per_g)
{
    __shared__ __attribute__((aligned(16))) unsigned char smem[2 * 49152 + 3 * A_PLANE * 2];
    unsigned short* ldsA = (unsigned short*)(smem + 2 * 49152);

    const int g    = blockIdx.x;
    const int tid  = threadIdx.x;
    const int lane = tid & 63;
    const int wv   = tid >> 6;        // 0..7
    const int wy   = wv & 3;          // row quarter (64 rows)
    const int wx   = wv >> 2;         // col half (128 cols)
    const int l31  = lane & 31;
    const int lh   = lane >> 5;

    // A-staging ownership: thread owns row r, k-half hf (16 consecutive floats)
    const int r  = tid >> 1;
    const int hf = tid & 1;
    const float* aptr = x + ((size_t)(g * NPG + r)) * FDIM + hf * 16;

    f32x16 acc[2][4];
    #pragma unroll
    for (int a = 0; a < 2; ++a)
        #pragma unroll
        for (int b = 0; b < 4; ++b)
            #pragma unroll
            for (int rr = 0; rr < 16; ++rr) acc[a][b][rr] = 0.f;

    float4 pf0, pf1, pf2, pf3;

    // ---- prolog: stage 0
    pf0 = *(const float4*)(aptr + 0);
    pf1 = *(const float4*)(aptr + 4);
    pf2 = *(const float4*)(aptr + 8);
    pf3 = *(const float4*)(aptr + 12);
    {
        const unsigned short* src = wsB;            // stage 0
        #pragma unroll
        for (int i = 0; i < 6; ++i) {
            const int unit = i * 512 + tid;
            __builtin_amdgcn_global_load_lds(
                (const __attribute__((address_space(1))) unsigned int*)(src + (size_t)unit * 8),
                (__attribute__((address_space(3))) unsigned int*)((unsigned short*)smem + unit * 8),
                16, 0, 0);
        }
    }
    // convert + write A(0) into LDS planes
    {
        float v[16] = {pf0.x, pf0.y, pf0.z, pf0.w, pf1.x, pf1.y, pf1.z, pf1.w,
                       pf2.x, pf2.y, pf2.z, pf2.w, pf3.x, pf3.y, pf3.z, pf3.w};
        unsigned short H[16], M[16], L[16];
        #pragma unroll
        for (int j = 0; j < 16; ++j) {
            float f1, f2, f3;
            H[j] = bf16_rne(v[j], &f1);
            float r1 = v[j] - f1;
            M[j] = bf16_rne(r1, &f2);
            float r2 = r1 - f2;
            L[j] = bf16_rne(r2, &f3);
        }
        const int base = r * A_ROW + hf * 16;
        const unsigned short* P[3] = {H, M, L};
        #pragma unroll
        for (int p = 0; p < 3; ++p) {
            const unsigned short* s8 = P[p];
            uint4 u0, u1;
            u0.x = (unsigned)s8[0] | ((unsigned)s8[1] << 16);
            u0.y = (unsigned)s8[2] | ((unsigned)s8[3] << 16);
            u0.z = (unsigned)s8[4] | ((unsigned)s8[5] << 16);
            u0.w = (unsigned)s8[6] | ((unsigned)s8[7] << 16);
            u1.x = (unsigned)s8[8] | ((unsigned)s8[9] << 16);
            u1.y = (unsigned)s8[10] | ((unsigned)s8[11] << 16);
            u1.z = (unsigned)s8[12] | ((unsigned)s8[13] << 16);
            u1.w = (unsigned)s8[14] | ((unsigned)s8[15] << 16);
            uint4* dst = (uint4*)(ldsA + p * A_PLANE + base);
            dst[0] = u0;
            dst[1] = u1;
        }
    }
    __syncthreads();

    // ---- main K loop
    for (int s = 0; s < STAGES; ++s) {
        if (s < STAGES - 1) {
            // B(s+1) async into the other buffer
            const unsigned short* src = wsB + (size_t)(s + 1) * BSTAGE_SHORTS;
            unsigned short* dstB = (unsigned short*)smem + ((s + 1) & 1) * BSTAGE_SHORTS;
            #pragma unroll
            for (int i = 0; i < 6; ++i) {
                const int unit = i * 512 + tid;
                __builtin_amdgcn_global_load_lds(
                    (const __attribute__((address_space(1))) unsigned int*)(src + (size_t)unit * 8),
                    (__attribute__((address_space(3))) unsigned int*)(dstB + unit * 8),
                    16, 0, 0);
            }
            // A(s+1) prefetch into regs
            const float* ap = aptr + (s + 1) * 32;
            pf0 = *(const float4*)(ap + 0);
            pf1 = *(const float4*)(ap + 4);
            pf2 = *(const float4*)(ap + 8);
            pf3 = *(const float4*)(ap + 12);
        }

        // compute stage s
        const bf16x8* bfp = (const bf16x8*)((unsigned short*)smem + (s & 1) * BSTAGE_SHORTS);
        #pragma unroll
        for (int q = 0; q < 2; ++q) {
            bf16x8 Bh[4], Bm[4], Bl[4];
            #pragma unroll
            for (int nt = 0; nt < 4; ++nt) {
                const int nn = wx * 4 + nt;
                Bh[nt] = bfp[((q * 3 + 0) * 8 + nn) * 64 + lane];
                Bm[nt] = bfp[((q * 3 + 1) * 8 + nn) * 64 + lane];
                Bl[nt] = bfp[((q * 3 + 2) * 8 + nn) * 64 + lane];
            }
            #pragma unroll
            for (int mt = 0; mt < 2; ++mt) {
                const int m = wy * 64 + mt * 32 + l31;
                const int aoff = m * A_ROW + q * 16 + lh * 8;
                bf16x8 Ah = *(const bf16x8*)(ldsA + 0 * A_PLANE + aoff);
                bf16x8 Am = *(const bf16x8*)(ldsA + 1 * A_PLANE + aoff);
                bf16x8 Al = *(const bf16x8*)(ldsA + 2 * A_PLANE + aoff);
                #pragma unroll
                for (int nt = 0; nt < 4; ++nt) {
                    acc[mt][nt] = __builtin_amdgcn_mfma_f32_32x32x16_bf16(Ah, Bh[nt], acc[mt][nt], 0, 0, 0);
                    acc[mt][nt] = __builtin_amdgcn_mfma_f32_32x32x16_bf16(Ah, Bm[nt], acc[mt][nt], 0, 0, 0);
                    acc[mt][nt] = __builtin_amdgcn_mfma_f32_32x32x16_bf16(Am, Bh[nt], acc[mt][nt], 0, 0, 0);
                    acc[mt][nt] = __builtin_amdgcn_mfma_f32_32x32x16_bf16(Ah, Bl[nt], acc[mt][nt], 0, 0, 0);
                    acc[mt][nt] = __builtin_amdgcn_mfma_f32_32x32x16_bf16(Al, Bh[nt], acc[mt][nt], 0, 0, 0);
                    acc[mt][nt] = __builtin_amdgcn_mfma_f32_32x32x16_bf16(Am, Bm[nt], acc[mt][nt], 0, 0, 0);
                }
            }
        }
        __syncthreads();   // drains vmcnt: B(s+1) + A(s+1) landed; all waves done with ldsA(s)/B(s)

        if (s < STAGES - 1) {
            float v[16] = {pf0.x, pf0.y, pf0.z, pf0.w, pf1.x, pf1.y, pf1.z, pf1.w,
                           pf2.x, pf2.y, pf2.z, pf2.w, pf3.x, pf3.y, pf3.z, pf3.w};
            unsigned short H[16], M[16], L[16];
            #pragma unroll
            for (int j = 0; j < 16; ++j) {
                float f1, f2, f3;
                H[j] = bf16_rne(v[j], &f1);
                float r1 = v[j] - f1;
                M[j] = bf16_rne(r1, &f2);
                float r2 = r1 - f2;
                L[j] = bf16_rne(r2, &f3);
            }
            const int base = r * A_ROW + hf * 16;
            const unsigned short* P[3] = {H, M, L};
            #pragma unroll
            for (int p = 0; p < 3; ++p) {
                const unsigned short* s8 = P[p];
                uint4 u0, u1;
                u0.x = (unsigned)s8[0] | ((unsigned)s8[1] << 16);
                u0.y = (unsigned)s8[2] | ((unsigned)s8[3] << 16);
                u0.z = (unsigned)s8[4] | ((unsigned)s8[5] << 16);
                u0.w = (unsigned)s8[6] | ((unsigned)s8[7] << 16);
                u1.x = (unsigned)s8[8] | ((unsigned)s8[9] << 16);
                u1.y = (unsigned)s8[10] | ((unsigned)s8[11] << 16);
                u1.z = (unsigned)s8[12] | ((unsigned)s8[13] << 16);
                u1.w = (unsigned)s8[14] | ((unsigned)s8[15] << 16);
                uint4* dst = (uint4*)(ldsA + p * A_PLANE + base);
                dst[0] = u0;
                dst[1] = u1;
            }
        }
        __syncthreads();   // ldsA(s+1) visible before next compute
    }

    // ---- epilogue (overlays the B-buffer region of smem)
    float* Sp   = (float*)smem;            // [2][256]
    float* sv   = Sp + 2 * NPG;            // [256]
    int*   selr = (int*)(sv + NPG);        // [128]
    float* redT = (float*)(selr + KSEL);   // [256]
    float* redS = redT + NPG;              // [256]

    float bb[4], ww[4];
    #pragma unroll
    for (int nt = 0; nt < 4; ++nt) {
        const int c = wx * 128 + nt * 32 + l31;
        bb[nt] = b1[c];
        ww[nt] = W2[c];
    }
    #pragma unroll
    for (int mt = 0; mt < 2; ++mt) {
        float pr[16];
        #pragma unroll
        for (int rr = 0; rr < 16; ++rr) pr[rr] = 0.f;
        #pragma unroll
        for (int nt = 0; nt < 4; ++nt)
            #pragma unroll
            for (int rr = 0; rr < 16; ++rr) {
                float h = acc[mt][nt][rr] + bb[nt];
                h = h > 0.f ? h : 0.f;
                pr[rr] = fmaf(h, ww[nt], pr[rr]);
            }
        #pragma unroll
        for (int mask = 1; mask <= 16; mask <<= 1)
            #pragma unroll
            for (int rr = 0; rr < 16; ++rr)
                pr[rr] += __shfl_xor(pr[rr], mask);
        if (l31 == 0) {
            #pragma unroll
            for (int rr = 0; rr < 16; ++rr) {
                const int row = wy * 64 + mt * 32 + (rr & 3) + 8 * (rr >> 2) + 4 * lh;
                Sp[wx * NPG + row] = pr[rr];
            }
        }
    }
    __syncthreads();

    float sc = 0.f;
    if (tid < NPG) {
        sc = b2[0] + Sp[tid] + Sp[NPG + tid];
        sv[tid] = sc;
    }
    __syncthreads();

    // selection: exact rank (score desc, index asc on ties)
    if (tid < NPG) {
        int rank = 0;
        for (int j = 0; j < NPG; ++j) {
            const float sj = sv[j];
            rank += (sj > sc || (sj == sc && j < tid)) ? 1 : 0;
        }
        const bool sel = rank < KSEL;
        mask_out[g * NPG + tid] = sel ? 1.0f : 0.0f;
        if (sel) selr[rank] = tid;
        redT[tid] = sc;
        redS[tid] = sel ? sc : 0.f;
    }
    __syncthreads();

    for (int off = 128; off > 0; off >>= 1) {
        if (tid < off) { redT[tid] += redT[tid + off]; redS[tid] += redS[tid + off]; }
        __syncthreads();
    }
    if (tid == 0) {
        const float tot = redT[0], ssum = redS[0];
        const float sel_mean = ssum * (1.0f / KSEL);
        const float uns_mean = (tot - ssum) * (1.0f / (NPG - KSEL));
        const float v = 0.5f - (sel_mean - uns_mean);
        loss_per_g[g] = v > 0.f ? v : 0.f;
    }

    // pooled gather; col per thread, rows L2/L3-warm
    const int col = tid;
    const float* __restrict__ xg = x + (size_t)g * NPG * FDIM;
    float a0 = 0.f, a1 = 0.f, a2 = 0.f, a3 = 0.f;
    #pragma unroll 4
    for (int n = 0; n < KSEL; n += 4) {
        a0 += xg[(size_t)selr[n + 0] * FDIM + col];
        a1 += xg[(size_t)selr[n + 1] * FDIM + col];
        a2 += xg[(size_t)selr[n + 2] * FDIM + col];
        a3 += xg[(size_t)selr[n + 3] * FDIM + col];
    }
    pooled[g * FDIM + col] = (a0 + a1) + (a2 + a3);
}

// ---------------------------------------------------------------------------
// K2: topk_loss = sum(loss_per_g) / B * 0.2
// ---------------------------------------------------------------------------
__global__ __launch_bounds__(256)
void loss_kernel(const float* __restrict__ loss_per_g, float* __restrict__ out_loss)
{
    __shared__ float red[256];
    const int t = threadIdx.x;
    red[t] = loss_per_g[t] + loss_per_g[t + 256];
    __syncthreads();
    for (int off = 128; off > 0; off >>= 1) {
        if (t < off) red[t] += red[t + off];
        __syncthreads();
    }
    if (t == 0) out_loss[0] = red[0] * (0.2f / BGRAPHS);
}

extern "C" void kernel_launch(void* const* d_in, const int* in_sizes, int n_in,
                              void* d_out, int out_size, void* d_ws, size_t ws_size,
                              hipStream_t stream)
{
    const float* x  = (const float*)d_in[0];
    const float* W1 = (const float*)d_in[2];
    const float* b1 = (const float*)d_in[3];
    const float* W2 = (const float*)d_in[4];
    const float* b2 = (const float*)d_in[5];

    float* out    = (float*)d_out;
    float* pooled = out;                       // [512*512]
    float* loss   = out + BGRAPHS * FDIM;      // [1]
    float* mask   = loss + 1;                  // [131072]

    float* loss_g       = (float*)d_ws;                               // 2 KB
    unsigned short* wsB = (unsigned short*)((char*)d_ws + 4096);      // 768 KB

    split_w1_kernel<<<192, 256, 0, stream>>>(W1, wsB);
    fused_kernel<<<BGRAPHS, 512, 0, stream>>>(x, wsB, b1, W2, b2,
                                              pooled, mask, loss_g);
    loss_kernel<<<1, 256, 0, stream>>>(loss_g, loss);
}